// Round 3
// baseline (721.634 us; speedup 1.0000x reference)
//
#include <hip/hip_runtime.h>
#include <hip/hip_bf16.h>
#include <math.h>

// Problem constants (GPT-2 small causal self-attention)
constexpr int Bz = 8;      // batch
constexpr int Tt = 1024;   // seq len
constexpr int Cc = 768;    // n_embd
constexpr int Hh = 12;     // heads
constexpr int Dd = 64;     // head dim
constexpr int BT = Bz * Tt;        // 8192 rows
constexpr int C3 = 3 * Cc;         // 2304

using bf16x8 = __attribute__((ext_vector_type(8))) short;
using u16x8  = __attribute__((ext_vector_type(8))) unsigned short;
using f32x4  = __attribute__((ext_vector_type(4))) float;

__device__ __forceinline__ unsigned short f2bf(float f) {
  unsigned int u = __builtin_bit_cast(unsigned int, f);
  u += 0x7fffu + ((u >> 16) & 1u);   // round-to-nearest-even
  return (unsigned short)(u >> 16);
}
__device__ __forceinline__ float bf2f(unsigned short u) {
  return __builtin_bit_cast(float, (unsigned int)u << 16);
}

// ---------------------------------------------------------------------------
// Transpose + cast: in[K][N] fp32 -> out[N][K] bf16.  block(32,8), grid(N/32,K/32)
// ---------------------------------------------------------------------------
__global__ __launch_bounds__(256) void tcast_kernel(
    const float* __restrict__ in, unsigned short* __restrict__ out, int K, int N) {
  __shared__ float t[32][33];
  const int tx = threadIdx.x, ty = threadIdx.y;
  const int kb = blockIdx.y * 32, nb = blockIdx.x * 32;
#pragma unroll
  for (int i = 0; i < 4; ++i)
    t[ty + 8 * i][tx] = in[(size_t)(kb + ty + 8 * i) * N + nb + tx];
  __syncthreads();
#pragma unroll
  for (int i = 0; i < 4; ++i)
    out[(size_t)(nb + ty + 8 * i) * K + kb + tx] = f2bf(t[tx][ty + 8 * i]);
}

// ---------------------------------------------------------------------------
// MFMA GEMM (B-transposed input): C[M][N] fp32 = A[M][K] * Bt[N][K]^T
// A is fp32 (cast during staging) or bf16; Bt is bf16.
// 128x128 tile, BK=32, 256 threads = 4 waves, each wave owns a 64x64 quadrant
// (4x4 fragments of 16x16, mfma_f32_16x16x32_bf16).
// Fragment layouts (m89-verified): A/B: elem[lane&15][(lane>>4)*8+b];
// D: row=(lane>>4)*4+r, col=lane&15.
// ---------------------------------------------------------------------------
template <bool A_IS_F32>
__global__ __launch_bounds__(256) void gemm_bt_kernel(
    const void* __restrict__ Av, const unsigned short* __restrict__ Bt,
    float* __restrict__ Cm, int M, int N, int K) {
  constexpr int BM = 128, BN = 128, BK = 32;
  __shared__ unsigned short As[BM][40];   // stride 40 (80 B): uniform bank spread
  __shared__ unsigned short Bs[BN][40];

  const int tid = threadIdx.x;
  const int wave = tid >> 6, lane = tid & 63;
  const int wr = wave >> 1, wc = wave & 1;     // wave -> 64x64 quadrant
  const int lr = lane & 15;                    // frag row (A/B), frag col (D)
  const int lg = lane >> 4;                    // k-group
  const int brow = blockIdx.y * BM, bcol = blockIdx.x * BN;

  f32x4 acc[4][4] = {};

  const int nT = K / BK;
  for (int kt = 0; kt < nT; ++kt) {
    const int k0 = kt * BK;
    __syncthreads();   // previous iter done reading LDS
    if constexpr (A_IS_F32) {
      const float* A = (const float*)Av;
#pragma unroll
      for (int i = 0; i < 4; ++i) {
        const int s = tid + 256 * i;          // 0..1023
        const int row = s >> 3;               // 0..127
        const int c4 = (s & 7) * 4;           // 0..28
        const float4 v = *(const float4*)(A + (size_t)(brow + row) * K + k0 + c4);
        ushort4 w;
        w.x = f2bf(v.x); w.y = f2bf(v.y); w.z = f2bf(v.z); w.w = f2bf(v.w);
        *(ushort4*)&As[row][c4] = w;
      }
    } else {
      const unsigned short* A = (const unsigned short*)Av;
#pragma unroll
      for (int i = 0; i < 2; ++i) {
        const int s = tid + 256 * i;          // 0..511
        const int row = s >> 2;               // 0..127
        const int c8 = (s & 3) * 8;           // 0,8,16,24
        const u16x8 v = *(const u16x8*)(A + (size_t)(brow + row) * K + k0 + c8);
        *(u16x8*)&As[row][c8] = v;
      }
    }
#pragma unroll
    for (int i = 0; i < 2; ++i) {
      const int s = tid + 256 * i;
      const int row = s >> 2;
      const int c8 = (s & 3) * 8;
      const u16x8 v = *(const u16x8*)(Bt + (size_t)(bcol + row) * K + k0 + c8);
      *(u16x8*)&Bs[row][c8] = v;
    }
    __syncthreads();

    bf16x8 af[4], bfr[4];
#pragma unroll
    for (int f = 0; f < 4; ++f) {
      af[f]  = *(const bf16x8*)&As[wr * 64 + f * 16 + lr][lg * 8];
      bfr[f] = *(const bf16x8*)&Bs[wc * 64 + f * 16 + lr][lg * 8];
    }
#pragma unroll
    for (int fi = 0; fi < 4; ++fi)
#pragma unroll
      for (int fj = 0; fj < 4; ++fj)
        acc[fi][fj] = __builtin_amdgcn_mfma_f32_16x16x32_bf16(
            af[fi], bfr[fj], acc[fi][fj], 0, 0, 0);
  }

  // Epilogue: C[brow + wr*64 + fi*16 + lg*4 + r][bcol + wc*64 + fj*16 + lr]
#pragma unroll
  for (int fi = 0; fi < 4; ++fi) {
    const size_t rbase = (size_t)(brow + wr * 64 + fi * 16 + lg * 4);
#pragma unroll
    for (int fj = 0; fj < 4; ++fj) {
      const int cbase = bcol + wc * 64 + fj * 16 + lr;
#pragma unroll
      for (int r = 0; r < 4; ++r)
        Cm[(rbase + r) * N + cbase] = acc[fi][fj][r];
    }
  }
}

// ---------------------------------------------------------------------------
// Flash-style causal attention, fp32 compute; P staged bf16; output bf16.
// Grid: (T/64, H, B). Block: 256 (16x16); thread owns 4x4 of S and O tiles.
// qkv layout: [BT][3C], q at h*64, k at C+h*64, v at 2C+h*64.
// Output yatt: [BT][C] bf16 (feeds GEMM2 directly).
// ---------------------------------------------------------------------------
__global__ __launch_bounds__(256) void attn_kernel(
    const float* __restrict__ qkv, unsigned short* __restrict__ y) {
  const int qt = blockIdx.x;
  const int h = blockIdx.y;
  const int b = blockIdx.z;
  const int qbase = qt * 64;

  const int tid = threadIdx.x;
  const int tx = tid & 15;
  const int ty = tid >> 4;

  __shared__ float Qs[64][65];
  __shared__ float Ks[64][65];
  __shared__ float Vs[64][65];
  __shared__ unsigned short Ps[64][68];   // bf16 P -> total LDS 57.2 KB

  const size_t rowstride = (size_t)C3;
  const float* qptr = qkv + (size_t)(b * Tt + qbase) * rowstride + h * Dd;

#pragma unroll
  for (int i = 0; i < 4; ++i) {
    const int id = tid + 256 * i;
    const int r = id >> 4;
    const int d4 = (id & 15) * 4;
    const float4 v = *(const float4*)(qptr + (size_t)r * rowstride + d4);
    Qs[r][d4 + 0] = v.x; Qs[r][d4 + 1] = v.y;
    Qs[r][d4 + 2] = v.z; Qs[r][d4 + 3] = v.w;
  }

  float o[4][4] = {};
  float m_run[4], l_run[4];
#pragma unroll
  for (int i = 0; i < 4; ++i) { m_run[i] = -INFINITY; l_run[i] = 0.0f; }

  const float scale = 0.125f;  // 1/sqrt(64)

  for (int kt = 0; kt <= qt; ++kt) {
    const int kbase = kt * 64;
    __syncthreads();
    const float* kptr = qkv + (size_t)(b * Tt + kbase) * rowstride + Cc + h * Dd;
    const float* vptr = qkv + (size_t)(b * Tt + kbase) * rowstride + 2 * Cc + h * Dd;
#pragma unroll
    for (int i = 0; i < 4; ++i) {
      const int id = tid + 256 * i;
      const int r = id >> 4;
      const int d4 = (id & 15) * 4;
      const float4 kv = *(const float4*)(kptr + (size_t)r * rowstride + d4);
      Ks[r][d4 + 0] = kv.x; Ks[r][d4 + 1] = kv.y;
      Ks[r][d4 + 2] = kv.z; Ks[r][d4 + 3] = kv.w;
      const float4 vv = *(const float4*)(vptr + (size_t)r * rowstride + d4);
      Vs[r][d4 + 0] = vv.x; Vs[r][d4 + 1] = vv.y;
      Vs[r][d4 + 2] = vv.z; Vs[r][d4 + 3] = vv.w;
    }
    __syncthreads();

    float s[4][4] = {};
#pragma unroll 8
    for (int d = 0; d < Dd; ++d) {
      float qv[4], kv[4];
#pragma unroll
      for (int i = 0; i < 4; ++i) qv[i] = Qs[ty * 4 + i][d];
#pragma unroll
      for (int j = 0; j < 4; ++j) kv[j] = Ks[tx * 4 + j][d];
#pragma unroll
      for (int i = 0; i < 4; ++i)
#pragma unroll
        for (int j = 0; j < 4; ++j) s[i][j] += qv[i] * kv[j];
    }

    const bool diag = (kt == qt);
#pragma unroll
    for (int i = 0; i < 4; ++i) {
      const int r = ty * 4 + i;
      float smax = -INFINITY;
#pragma unroll
      for (int j = 0; j < 4; ++j) {
        const int c = tx * 4 + j;
        float v = s[i][j] * scale;
        if (diag && c > r) v = -INFINITY;
        s[i][j] = v;
        smax = fmaxf(smax, v);
      }
#pragma unroll
      for (int off = 1; off < 16; off <<= 1)
        smax = fmaxf(smax, __shfl_xor(smax, off));
      const float mnew = fmaxf(m_run[i], smax);
      float lloc = 0.0f;
#pragma unroll
      for (int j = 0; j < 4; ++j) {
        const float p = (s[i][j] == -INFINITY) ? 0.0f : expf(s[i][j] - mnew);
        s[i][j] = p;
        lloc += p;
      }
#pragma unroll
      for (int off = 1; off < 16; off <<= 1)
        lloc += __shfl_xor(lloc, off);
      const float alpha = expf(m_run[i] - mnew);
      l_run[i] = l_run[i] * alpha + lloc;
      m_run[i] = mnew;
#pragma unroll
      for (int j = 0; j < 4; ++j) o[i][j] *= alpha;
#pragma unroll
      for (int j = 0; j < 4; ++j) Ps[r][tx * 4 + j] = f2bf(s[i][j]);
    }
    __syncthreads();

#pragma unroll 8
    for (int c = 0; c < 64; ++c) {
      float pv[4], vv[4];
#pragma unroll
      for (int i = 0; i < 4; ++i) pv[i] = bf2f(Ps[ty * 4 + i][c]);
#pragma unroll
      for (int j = 0; j < 4; ++j) vv[j] = Vs[c][tx * 4 + j];
#pragma unroll
      for (int i = 0; i < 4; ++i)
#pragma unroll
        for (int j = 0; j < 4; ++j) o[i][j] += pv[i] * vv[j];
    }
  }

#pragma unroll
  for (int i = 0; i < 4; ++i) {
    const int r = ty * 4 + i;
    const float inv_l = 1.0f / l_run[i];
    ushort4 w;
    w.x = f2bf(o[i][0] * inv_l);
    w.y = f2bf(o[i][1] * inv_l);
    w.z = f2bf(o[i][2] * inv_l);
    w.w = f2bf(o[i][3] * inv_l);
    *(ushort4*)(y + (size_t)(b * Tt + qbase + r) * Cc + h * Dd + tx * 4) = w;
  }
}

// ---------------------------------------------------------------------------
extern "C" void kernel_launch(void* const* d_in, const int* in_sizes, int n_in,
                              void* d_out, int out_size, void* d_ws, size_t ws_size,
                              hipStream_t stream) {
  const float* x = (const float*)d_in[0];        // [8,1024,768]
  const float* w_attn = (const float*)d_in[1];   // [768, 2304]
  const float* w_proj = (const float*)d_in[2];   // [768, 768]
  float* out = (float*)d_out;                    // [8,1024,768] fp32

  // workspace: qkv fp32 | yatt bf16 | waT bf16 | wpT bf16  (~92.8 MB)
  float* qkv = (float*)d_ws;                                   // [8192][2304]
  unsigned short* yatt = (unsigned short*)(qkv + (size_t)BT * C3);  // [8192][768]
  unsigned short* waT = yatt + (size_t)BT * Cc;                // [2304][768]
  unsigned short* wpT = waT + (size_t)C3 * Cc;                 // [768][768]

  // 0) weight transpose+cast (tiny)
  tcast_kernel<<<dim3(C3 / 32, Cc / 32), dim3(32, 8), 0, stream>>>(w_attn, waT, Cc, C3);
  tcast_kernel<<<dim3(Cc / 32, Cc / 32), dim3(32, 8), 0, stream>>>(w_proj, wpT, Cc, Cc);

  // 1) qkv = x @ w_attn   (A fp32 cast-on-stage, B = waT bf16)
  gemm_bt_kernel<true><<<dim3(C3 / 128, BT / 128), 256, 0, stream>>>(
      x, waT, qkv, BT, C3, Cc);

  // 2) flash attention (fp32 compute, bf16 output)
  attn_kernel<<<dim3(Tt / 64, Hh, Bz), 256, 0, stream>>>(qkv, yatt);

  // 3) out = yatt @ w_proj  (A bf16, B = wpT bf16)
  gemm_bt_kernel<false><<<dim3(Cc / 128, BT / 128), 256, 0, stream>>>(
      yatt, wpT, out, BT, Cc, Cc);
}

// Round 4
// 260.957 us; speedup vs baseline: 2.7653x; 2.7653x over previous
//
#include <hip/hip_runtime.h>
#include <hip/hip_bf16.h>
#include <math.h>

// Problem constants (GPT-2 small causal self-attention)
constexpr int Bz = 8;      // batch
constexpr int Tt = 1024;   // seq len
constexpr int Cc = 768;    // n_embd
constexpr int Hh = 12;     // heads
constexpr int Dd = 64;     // head dim
constexpr int BT = Bz * Tt;        // 8192 rows
constexpr int C3 = 3 * Cc;         // 2304

using bf16x8 = __attribute__((ext_vector_type(8))) short;
using u16x8  = __attribute__((ext_vector_type(8))) unsigned short;
using f32x4  = __attribute__((ext_vector_type(4))) float;

__device__ __forceinline__ unsigned short f2bf(float f) {
  unsigned int u = __builtin_bit_cast(unsigned int, f);
  u += 0x7fffu + ((u >> 16) & 1u);   // round-to-nearest-even
  return (unsigned short)(u >> 16);
}

// ---------------------------------------------------------------------------
// Transpose + cast: in[K][N] fp32 -> out[N][K] bf16.  block(32,8), grid(N/32,K/32)
// ---------------------------------------------------------------------------
__global__ __launch_bounds__(256) void tcast_kernel(
    const float* __restrict__ in, unsigned short* __restrict__ out, int K, int N) {
  __shared__ float t[32][33];
  const int tx = threadIdx.x, ty = threadIdx.y;
  const int kb = blockIdx.y * 32, nb = blockIdx.x * 32;
#pragma unroll
  for (int i = 0; i < 4; ++i)
    t[ty + 8 * i][tx] = in[(size_t)(kb + ty + 8 * i) * N + nb + tx];
  __syncthreads();
#pragma unroll
  for (int i = 0; i < 4; ++i)
    out[(size_t)(nb + ty + 8 * i) * K + kb + tx] = f2bf(t[tx][ty + 8 * i]);
}

// ---------------------------------------------------------------------------
// GEMM1 (fused QKV projection): qkv = x[8192][768] @ waT[2304][768]^T,
// epilogue scatters bf16 into q[B][H][T][D], k[B][H][T][D], v^T[B][H][D][T].
// 128x128 tile, BK=32, 4 waves; mfma_f32_16x16x32_bf16 (m89 layouts).
// ---------------------------------------------------------------------------
__global__ __launch_bounds__(256) void gemm_qkv_kernel(
    const float* __restrict__ A, const unsigned short* __restrict__ Bt,
    unsigned short* __restrict__ qh, unsigned short* __restrict__ kh,
    unsigned short* __restrict__ vtg) {
  constexpr int BM = 128, BN = 128, BK = 32;
  const int M = BT, N = C3, K = Cc;
  (void)M; (void)N;
  __shared__ unsigned short As[BM][40];
  __shared__ unsigned short Bs[BN][40];

  const int tid = threadIdx.x;
  const int wave = tid >> 6, lane = tid & 63;
  const int wr = wave >> 1, wc = wave & 1;
  const int lr = lane & 15;
  const int lg = lane >> 4;
  const int brow = blockIdx.y * BM, bcol = blockIdx.x * BN;

  f32x4 acc[4][4] = {};

  const int nT = K / BK;
  for (int kt = 0; kt < nT; ++kt) {
    const int k0 = kt * BK;
    __syncthreads();
#pragma unroll
    for (int i = 0; i < 4; ++i) {
      const int s = tid + 256 * i;          // 0..1023
      const int row = s >> 3;               // 0..127
      const int c4 = (s & 7) * 4;           // 0..28
      const float4 v = *(const float4*)(A + (size_t)(brow + row) * K + k0 + c4);
      ushort4 w;
      w.x = f2bf(v.x); w.y = f2bf(v.y); w.z = f2bf(v.z); w.w = f2bf(v.w);
      *(ushort4*)&As[row][c4] = w;
    }
#pragma unroll
    for (int i = 0; i < 2; ++i) {
      const int s = tid + 256 * i;
      const int row = s >> 2;
      const int c8 = (s & 3) * 8;
      *(u16x8*)&Bs[row][c8] = *(const u16x8*)(Bt + (size_t)(bcol + row) * K + k0 + c8);
    }
    __syncthreads();

    bf16x8 af[4], bfr[4];
#pragma unroll
    for (int f = 0; f < 4; ++f) {
      af[f]  = *(const bf16x8*)&As[wr * 64 + f * 16 + lr][lg * 8];
      bfr[f] = *(const bf16x8*)&Bs[wc * 64 + f * 16 + lr][lg * 8];
    }
#pragma unroll
    for (int fi = 0; fi < 4; ++fi)
#pragma unroll
      for (int fj = 0; fj < 4; ++fj)
        acc[fi][fj] = __builtin_amdgcn_mfma_f32_16x16x32_bf16(
            af[fi], bfr[fj], acc[fi][fj], 0, 0, 0);
  }

  // Epilogue: n in one region per block (768 % 128 == 0).
  const int region = bcol / Cc;        // 0=q, 1=k, 2=v
  const int nb = bcol - region * Cc;
#pragma unroll
  for (int fi = 0; fi < 4; ++fi) {
    const int m0 = brow + wr * 64 + fi * 16 + lg * 4;
    const int b_ = m0 >> 10, t0 = m0 & 1023;
#pragma unroll
    for (int fj = 0; fj < 4; ++fj) {
      const int n = nb + wc * 64 + fj * 16 + lr;
      const int h_ = n >> 6, d_ = n & 63;
      if (region < 2) {
        unsigned short* dst = (region == 0 ? qh : kh) +
            (((size_t)(b_ * Hh + h_)) * Tt + t0) * Dd + d_;
#pragma unroll
        for (int r = 0; r < 4; ++r) dst[(size_t)r * Dd] = f2bf(acc[fi][fj][r]);
      } else {
        ushort4 w;
        w.x = f2bf(acc[fi][fj][0]);
        w.y = f2bf(acc[fi][fj][1]);
        w.z = f2bf(acc[fi][fj][2]);
        w.w = f2bf(acc[fi][fj][3]);
        *(ushort4*)(vtg + (((size_t)(b_ * Hh + h_)) * Dd + d_) * Tt + t0) = w;
      }
    }
  }
}

// ---------------------------------------------------------------------------
// MFMA GEMM (B-transposed, bf16 A): C[M][N] fp32 = A[M][K] * Bt[N][K]^T
// ---------------------------------------------------------------------------
__global__ __launch_bounds__(256) void gemm_bt_kernel(
    const unsigned short* __restrict__ A, const unsigned short* __restrict__ Bt,
    float* __restrict__ Cm, int M, int N, int K) {
  constexpr int BM = 128, BN = 128, BK = 32;
  __shared__ unsigned short As[BM][40];
  __shared__ unsigned short Bs[BN][40];

  const int tid = threadIdx.x;
  const int wave = tid >> 6, lane = tid & 63;
  const int wr = wave >> 1, wc = wave & 1;
  const int lr = lane & 15;
  const int lg = lane >> 4;
  const int brow = blockIdx.y * BM, bcol = blockIdx.x * BN;

  f32x4 acc[4][4] = {};

  const int nT = K / BK;
  for (int kt = 0; kt < nT; ++kt) {
    const int k0 = kt * BK;
    __syncthreads();
#pragma unroll
    for (int i = 0; i < 2; ++i) {
      const int s = tid + 256 * i;
      const int row = s >> 2;
      const int c8 = (s & 3) * 8;
      *(u16x8*)&As[row][c8] = *(const u16x8*)(A + (size_t)(brow + row) * K + k0 + c8);
      *(u16x8*)&Bs[row][c8] = *(const u16x8*)(Bt + (size_t)(bcol + row) * K + k0 + c8);
    }
    __syncthreads();

    bf16x8 af[4], bfr[4];
#pragma unroll
    for (int f = 0; f < 4; ++f) {
      af[f]  = *(const bf16x8*)&As[wr * 64 + f * 16 + lr][lg * 8];
      bfr[f] = *(const bf16x8*)&Bs[wc * 64 + f * 16 + lr][lg * 8];
    }
#pragma unroll
    for (int fi = 0; fi < 4; ++fi)
#pragma unroll
      for (int fj = 0; fj < 4; ++fj)
        acc[fi][fj] = __builtin_amdgcn_mfma_f32_16x16x32_bf16(
            af[fi], bfr[fj], acc[fi][fj], 0, 0, 0);
  }

#pragma unroll
  for (int fi = 0; fi < 4; ++fi) {
    const size_t rbase = (size_t)(brow + wr * 64 + fi * 16 + lg * 4);
#pragma unroll
    for (int fj = 0; fj < 4; ++fj) {
      const int cbase = bcol + wc * 64 + fj * 16 + lr;
#pragma unroll
      for (int r = 0; r < 4; ++r)
        Cm[(rbase + r) * N + cbase] = acc[fi][fj][r];
    }
  }
}

// ---------------------------------------------------------------------------
// MFMA flash attention, bf16 inputs, f32 softmax (exp2 domain), bf16 out.
// Grid: (T/64, H, B), 256 threads = 4 waves; wave w owns q rows [w*16, w*16+16).
// q,k: [B][H][T][D] bf16;  v^T: [B][H][D][T] bf16;  y: [BT][C] bf16.
// Per KV tile (64): QK^T = 8 MFMA/wave, softmax in regs, P via wave-private
// LDS strip (no barrier needed), PV = 8 MFMA/wave.
// ---------------------------------------------------------------------------
__global__ __launch_bounds__(256) void attn_mfma_kernel(
    const unsigned short* __restrict__ qh, const unsigned short* __restrict__ kh,
    const unsigned short* __restrict__ vtg, unsigned short* __restrict__ y) {
  const int qt = blockIdx.x;
  const int h = blockIdx.y;
  const int b = blockIdx.z;
  const int qbase = qt * 64;

  const int tid = threadIdx.x;
  const int wave = tid >> 6, lane = tid & 63;
  const int lr = lane & 15;
  const int lg = lane >> 4;

  __shared__ unsigned short Ks[64][72];   // [tk][d]   stride 72: uniform banks
  __shared__ unsigned short Vt[64][72];   // [d][tk]
  __shared__ unsigned short Ps[64][72];   // [q][tk]   wave-private strips

  const size_t head = ((size_t)(b * Hh + h)) * Tt * Dd;

  // Q fragments (registers, reused across all KV tiles)
  bf16x8 qf[2];
  {
    const unsigned short* qp = qh + head + (size_t)(qbase + wave * 16 + lr) * Dd;
    qf[0] = *(const bf16x8*)(qp + lg * 8);
    qf[1] = *(const bf16x8*)(qp + 32 + lg * 8);
  }

  f32x4 o[4] = {};
  float m_run[4], l_run[4];
#pragma unroll
  for (int r = 0; r < 4; ++r) { m_run[r] = -INFINITY; l_run[r] = 0.0f; }

  constexpr float kS = 0.125f * 1.4426950408889634f;  // scale * log2(e)

  for (int kt = 0; kt <= qt; ++kt) {
    const int kbase = kt * 64;
    __syncthreads();   // all waves done reading Ks/Vt of prev tile
    {
      const unsigned short* kp = kh + head + (size_t)kbase * Dd;
      const unsigned short* vp = vtg + head + kbase;
#pragma unroll
      for (int it = 0; it < 2; ++it) {
        const int s = tid + 256 * it;       // 0..511
        const int row = s >> 3;             // 0..63
        const int c8 = (s & 7) * 8;         // 0..56
        *(u16x8*)&Ks[row][c8] = *(const u16x8*)(kp + (size_t)row * Dd + c8);
        *(u16x8*)&Vt[row][c8] = *(const u16x8*)(vp + (size_t)row * Tt + c8);
      }
    }
    __syncthreads();

    // ---- S = Q K^T (f32 accum) ----
    f32x4 s_acc[4];
#pragma unroll
    for (int j = 0; j < 4; ++j) {
      const bf16x8 kf0 = *(const bf16x8*)&Ks[j * 16 + lr][lg * 8];
      const bf16x8 kf1 = *(const bf16x8*)&Ks[j * 16 + lr][32 + lg * 8];
      f32x4 t = {};
      t = __builtin_amdgcn_mfma_f32_16x16x32_bf16(qf[0], kf0, t, 0, 0, 0);
      t = __builtin_amdgcn_mfma_f32_16x16x32_bf16(qf[1], kf1, t, 0, 0, 0);
      s_acc[j] = t;
    }

    // ---- online softmax (exp2 domain), rows q = lg*4 + r of wave strip ----
    const bool diag = (kt == qt);
#pragma unroll
    for (int r = 0; r < 4; ++r) {
      const int qrow = qbase + wave * 16 + lg * 4 + r;
      float mx = -INFINITY;
#pragma unroll
      for (int j = 0; j < 4; ++j) {
        float v = s_acc[j][r] * kS;
        if (diag && (kbase + j * 16 + lr) > qrow) v = -INFINITY;
        s_acc[j][r] = v;
        mx = fmaxf(mx, v);
      }
#pragma unroll
      for (int off = 1; off < 16; off <<= 1)
        mx = fmaxf(mx, __shfl_xor(mx, off));
      const float mnew = fmaxf(m_run[r], mx);
      float ls = 0.0f;
#pragma unroll
      for (int j = 0; j < 4; ++j) {
        const float p = exp2f(s_acc[j][r] - mnew);
        s_acc[j][r] = p;
        ls += p;
      }
#pragma unroll
      for (int off = 1; off < 16; off <<= 1)
        ls += __shfl_xor(ls, off);
      const float alpha = exp2f(m_run[r] - mnew);   // 0 on first tile
      l_run[r] = l_run[r] * alpha + ls;
      m_run[r] = mnew;
#pragma unroll
      for (int jd = 0; jd < 4; ++jd) o[jd][r] *= alpha;
    }

    // ---- P -> LDS (wave-private strip), read back as A-fragments ----
#pragma unroll
    for (int j = 0; j < 4; ++j)
#pragma unroll
      for (int r = 0; r < 4; ++r)
        Ps[wave * 16 + lg * 4 + r][j * 16 + lr] = f2bf(s_acc[j][r]);

#pragma unroll
    for (int c = 0; c < 2; ++c) {
      const bf16x8 pa = *(const bf16x8*)&Ps[wave * 16 + lr][c * 32 + lg * 8];
#pragma unroll
      for (int jd = 0; jd < 4; ++jd) {
        const bf16x8 vf = *(const bf16x8*)&Vt[jd * 16 + lr][c * 32 + lg * 8];
        o[jd] = __builtin_amdgcn_mfma_f32_16x16x32_bf16(pa, vf, o[jd], 0, 0, 0);
      }
    }
  }

  // ---- write O / l  (y is [BT][C] bf16) ----
#pragma unroll
  for (int r = 0; r < 4; ++r) {
    const float inv = 1.0f / l_run[r];
    const size_t row = (size_t)(b * Tt + qbase + wave * 16 + lg * 4 + r);
#pragma unroll
    for (int jd = 0; jd < 4; ++jd)
      y[row * Cc + h * Dd + jd * 16 + lr] = f2bf(o[jd][r] * inv);
  }
}

// ---------------------------------------------------------------------------
extern "C" void kernel_launch(void* const* d_in, const int* in_sizes, int n_in,
                              void* d_out, int out_size, void* d_ws, size_t ws_size,
                              hipStream_t stream) {
  const float* x = (const float*)d_in[0];        // [8,1024,768]
  const float* w_attn = (const float*)d_in[1];   // [768, 2304]
  const float* w_proj = (const float*)d_in[2];   // [768, 768]
  float* out = (float*)d_out;                    // [8,1024,768] fp32

  const size_t headTD = (size_t)Bz * Hh * Tt * Dd;   // 6.29M elems
  unsigned short* qh   = (unsigned short*)d_ws;      // [B][H][T][D]
  unsigned short* kh   = qh + headTD;                // [B][H][T][D]
  unsigned short* vtg  = kh + headTD;                // [B][H][D][T]
  unsigned short* yatt = vtg + headTD;               // [BT][Cc]
  unsigned short* waT  = yatt + (size_t)BT * Cc;     // [2304][768]
  unsigned short* wpT  = waT + (size_t)C3 * Cc;      // [768][768]

  // 0) weight transpose+cast (tiny)
  tcast_kernel<<<dim3(C3 / 32, Cc / 32), dim3(32, 8), 0, stream>>>(w_attn, waT, Cc, C3);
  tcast_kernel<<<dim3(Cc / 32, Cc / 32), dim3(32, 8), 0, stream>>>(w_proj, wpT, Cc, Cc);

  // 1) fused QKV projection with layout-shuffled bf16 outputs
  gemm_qkv_kernel<<<dim3(C3 / 128, BT / 128), 256, 0, stream>>>(x, waT, qh, kh, vtg);

  // 2) MFMA flash attention
  attn_mfma_kernel<<<dim3(Tt / 64, Hh, Bz), 256, 0, stream>>>(qh, kh, vtg, yatt);

  // 3) out = yatt @ w_proj
  gemm_bt_kernel<<<dim3(Cc / 128, BT / 128), 256, 0, stream>>>(
      yatt, wpT, out, BT, Cc, Cc);
}